// Round 1
// baseline (15702.943 us; speedup 1.0000x reference)
//
#include <hip/hip_runtime.h>
#include <hip/hip_bf16.h>
#include <cstdint>

// Problem constants (from reference): H=512, B=64, S=512, D=512, N_AUX=2
#define B_ 64
#define S_ 512
#define D_ 512
#define H_ 512
#define M_ (B_*S_)   // 32768 rows for the projection GEMMs
#define G3_ (3*H_)   // 1536
#define G2_ (2*H_)   // 1024

using floatx4 = __attribute__((ext_vector_type(4))) float;
using shortx8 = __attribute__((ext_vector_type(8))) short;

__device__ __forceinline__ unsigned short f32_to_bf16(float f) {
    union { float f; uint32_t u; } v; v.f = f;
    uint32_t u = v.u;
    return (unsigned short)((u + 0x7FFFu + ((u >> 16) & 1u)) >> 16);
}
__device__ __forceinline__ float bf16_to_f32(unsigned short s) {
    union { uint32_t u; float f; } v; v.u = ((uint32_t)s) << 16;
    return v.f;
}

// ---------------------------------------------------------------------------
// Projection GEMM: out[m][n] = scale * ( sum_a  X_a[m,:] . W_a[n,:]  + sum_a bias_a[n] )
// X fp32 [streams][M][D], W fp32 [streams][N][D], out bf16 [M][N].
// One 16x16 C-tile per wave; K-loop of 16 x (16x16x32 bf16 MFMA).
// Fragment layouts (verified m89/m120):
//   A: lane holds A[m=lane&15][k = (lane>>4)*8 + j], j=0..7
//   B: lane holds B[n=lane&15][k = (lane>>4)*8 + j]
//   D: lane reg r holds D[m=(lane>>4)*4+r][n=lane&15]
// ---------------------------------------------------------------------------
__global__ __launch_bounds__(256) void proj_gemm(
    const float* __restrict__ X, const float* __restrict__ W,
    const float* __restrict__ bias, unsigned short* __restrict__ out,
    int N, int nstreams, float scale, size_t x_stride, size_t w_stride)
{
    const int m0   = blockIdx.x * 16;
    const int wave = threadIdx.x >> 6;
    const int lane = threadIdx.x & 63;
    const int n0   = blockIdx.y * 64 + wave * 16;
    const int row_a = m0 + (lane & 15);
    const int row_b = n0 + (lane & 15);
    const int koff  = (lane >> 4) * 8;

    floatx4 acc = {0.f, 0.f, 0.f, 0.f};

    for (int a = 0; a < nstreams; ++a) {
        const float* Xa = X + (size_t)a * x_stride + (size_t)row_a * D_ + koff;
        const float* Wa = W + (size_t)a * w_stride + (size_t)row_b * D_ + koff;
        #pragma unroll 4
        for (int kt = 0; kt < D_ / 32; ++kt) {
            const floatx4* px = (const floatx4*)(Xa + kt * 32);
            const floatx4* pw = (const floatx4*)(Wa + kt * 32);
            floatx4 x0 = px[0], x1 = px[1];
            floatx4 w0 = pw[0], w1 = pw[1];
            shortx8 af, bf;
            #pragma unroll
            for (int j = 0; j < 4; ++j) {
                af[j]     = (short)f32_to_bf16(x0[j]);
                af[j + 4] = (short)f32_to_bf16(x1[j]);
                bf[j]     = (short)f32_to_bf16(w0[j]);
                bf[j + 4] = (short)f32_to_bf16(w1[j]);
            }
            acc = __builtin_amdgcn_mfma_f32_16x16x32_bf16(af, bf, acc, 0, 0, 0);
        }
    }

    const int n = n0 + (lane & 15);
    float bsum = 0.f;
    for (int a = 0; a < nstreams; ++a) bsum += bias[a * N + n];
    #pragma unroll
    for (int r = 0; r < 4; ++r) {
        int m = m0 + (lane >> 4) * 4 + r;
        out[(size_t)m * N + n] = f32_to_bf16(scale * (acc[r] + bsum));
    }
}

// ---------------------------------------------------------------------------
// Transpose bf16 [B][S][G] (i.e. [M][G], m=b*S+s) -> [S][G][B] so the scan
// reads lane-coalesced along batch.
// ---------------------------------------------------------------------------
__global__ __launch_bounds__(256) void transpose_to_sgb(
    const unsigned short* __restrict__ in, unsigned short* __restrict__ out, int G)
{
    __shared__ unsigned short tile[64][66];   // [b][g] ; 66*2B=132B rows -> 33-dword stride, conflict-free
    const int s  = blockIdx.x;
    const int g0 = blockIdx.y * 64;
    const int c  = threadIdx.x & 63;
    const int r0 = threadIdx.x >> 6;          // 0..3
    #pragma unroll
    for (int i = 0; i < 16; ++i) {
        int b = r0 * 16 + i;
        tile[b][c] = in[((size_t)(b * S_ + s)) * G + g0 + c];  // coalesced in g
    }
    __syncthreads();
    #pragma unroll
    for (int i = 0; i < 16; ++i) {
        int gg = r0 * 16 + i;
        out[((size_t)s * G + g0 + gg) * 64 + c] = tile[c][gg]; // coalesced in b
    }
}

// hx fp32 [B][H] -> ht0 fp32 [H][B]
__global__ __launch_bounds__(256) void transpose_h0(
    const float* __restrict__ hx, float* __restrict__ ht0)
{
    __shared__ float tile[64][65];
    const int k0 = blockIdx.x * 64;
    const int c  = threadIdx.x & 63;
    const int r0 = threadIdx.x >> 6;
    #pragma unroll
    for (int i = 0; i < 16; ++i) {
        int b = r0 * 16 + i;
        tile[b][c] = hx[(size_t)b * H_ + k0 + c];
    }
    __syncthreads();
    #pragma unroll
    for (int i = 0; i < 16; ++i) {
        int kk = r0 * 16 + i;
        ht0[(size_t)(k0 + kk) * 64 + c] = tile[c][kk];
    }
}

// ---------------------------------------------------------------------------
// One scan step. 128 blocks x 256 threads; block owns 4 hidden columns j,
// thread = (b = lane, j = blk*4 + tid>>6). W_hh rows are wave-uniform reads
// (L1 broadcast); h is [H][B] so reads are lane-coalesced.
// ---------------------------------------------------------------------------
__global__ __launch_bounds__(256) void scan_step(
    const float* __restrict__ h_in, float* __restrict__ h_out,
    const unsigned short* __restrict__ gi_t,  // [S][3H][B] bf16
    const unsigned short* __restrict__ f_t,   // [S][2H][B] bf16
    const float* __restrict__ Whh,            // [3H][H]
    const float* __restrict__ bhh,            // [3H]
    float* __restrict__ ys,                   // [S][H][B]
    int t)
{
    const int b  = threadIdx.x & 63;
    const int jl = threadIdx.x >> 6;
    const int j  = blockIdx.x * 4 + jl;

    const float* wr = Whh + (size_t)j * H_;
    const float* wi = Whh + (size_t)(H_ + j) * H_;
    const float* wn = Whh + (size_t)(2 * H_ + j) * H_;

    float ar = 0.f, ai = 0.f, an = 0.f;
    #pragma unroll 2
    for (int k = 0; k < H_; k += 4) {
        floatx4 w4r = *(const floatx4*)(wr + k);
        floatx4 w4i = *(const floatx4*)(wi + k);
        floatx4 w4n = *(const floatx4*)(wn + k);
        float h0 = h_in[(k + 0) * 64 + b];
        float h1 = h_in[(k + 1) * 64 + b];
        float h2 = h_in[(k + 2) * 64 + b];
        float h3 = h_in[(k + 3) * 64 + b];
        ar += w4r[0] * h0 + w4r[1] * h1 + w4r[2] * h2 + w4r[3] * h3;
        ai += w4i[0] * h0 + w4i[1] * h1 + w4i[2] * h2 + w4i[3] * h3;
        an += w4n[0] * h0 + w4n[1] * h1 + w4n[2] * h2 + w4n[3] * h3;
    }

    const float hr = ar + bhh[j];
    const float hi = ai + bhh[H_ + j];
    const float hn = an + bhh[2 * H_ + j];

    const unsigned short* gp = gi_t + ((size_t)t * G3_ + j) * 64 + b;
    const float ir  = bf16_to_f32(gp[0]);
    const float ii  = bf16_to_f32(gp[(size_t)H_ * 64]);
    const float inn = bf16_to_f32(gp[(size_t)2 * H_ * 64]);
    const unsigned short* fp = f_t + ((size_t)t * G2_ + j) * 64 + b;
    const float fr = bf16_to_f32(fp[0]);
    const float fi = bf16_to_f32(fp[(size_t)H_ * 64]);

    const float rg = 1.f / (1.f + __expf(-(ir + hr + fr)));
    const float ig = 1.f / (1.f + __expf(-(ii + hi + fi)));
    const float ng = tanhf(inn + rg * hn);
    const float hprev = h_in[(size_t)j * 64 + b];
    const float hy = ng + ig * (hprev - ng);

    h_out[(size_t)j * 64 + b] = hy;
    ys[((size_t)t * H_ + j) * 64 + b] = hy;
}

// ys [S][H][B] -> out [B][S][H]; s==S-1 slab also written to h_final [B][H]
__global__ __launch_bounds__(256) void transpose_out(
    const float* __restrict__ ys, float* __restrict__ out, float* __restrict__ hfin)
{
    __shared__ float tile[64][65];   // [j][b]
    const int s  = blockIdx.x;
    const int j0 = blockIdx.y * 64;
    const int c  = threadIdx.x & 63;
    const int r0 = threadIdx.x >> 6;
    #pragma unroll
    for (int i = 0; i < 16; ++i) {
        int jj = r0 * 16 + i;
        tile[jj][c] = ys[((size_t)s * H_ + j0 + jj) * 64 + c];  // coalesced in b
    }
    __syncthreads();
    #pragma unroll
    for (int i = 0; i < 16; ++i) {
        int b = r0 * 16 + i;
        float v = tile[c][b];
        out[(size_t)b * (S_ * H_) + (size_t)s * H_ + j0 + c] = v; // coalesced in j
        if (s == S_ - 1) hfin[(size_t)b * H_ + j0 + c] = v;
    }
}

extern "C" void kernel_launch(void* const* d_in, const int* in_sizes, int n_in,
                              void* d_out, int out_size, void* d_ws, size_t ws_size,
                              hipStream_t stream) {
    const float* input_feats = (const float*)d_in[0];  // [B,S,D]
    const float* aux_feats   = (const float*)d_in[1];  // [A,B,S,D]
    const float* hx          = (const float*)d_in[2];  // [B,H]
    const float* w_ih        = (const float*)d_in[3];  // [3H,D]
    const float* w_fh        = (const float*)d_in[4];  // [A,2H,D]
    const float* b_ih        = (const float*)d_in[5];  // [3H]
    const float* b_fh        = (const float*)d_in[6];  // [A,2H]
    const float* w_hh        = (const float*)d_in[7];  // [3H,H]
    const float* b_hh        = (const float*)d_in[8];  // [3H]
    float* out = (float*)d_out;

    // workspace layout (~403 MB)
    char* ws = (char*)d_ws;
    size_t off = 0;
    unsigned short* gi_b = (unsigned short*)(ws + off); off += (size_t)M_ * G3_ * 2;   // 100.7 MB
    unsigned short* f_b  = (unsigned short*)(ws + off); off += (size_t)M_ * G2_ * 2;   //  67.1 MB
    unsigned short* gi_t = (unsigned short*)(ws + off); off += (size_t)M_ * G3_ * 2;   // 100.7 MB
    unsigned short* f_t  = (unsigned short*)(ws + off); off += (size_t)M_ * G2_ * 2;   //  67.1 MB
    float* ys            = (float*)(ws + off);          off += (size_t)S_ * H_ * B_ * 4; // 67.1 MB
    float* ht            = (float*)(ws + off);          off += (size_t)2 * H_ * B_ * 4;  // 256 KB

    dim3 blk(256);

    // gi = input @ W_ih^T + b_ih    (bf16 MFMA, fp32 accum)
    proj_gemm<<<dim3(M_ / 16, G3_ / 64), blk, 0, stream>>>(
        input_feats, w_ih, b_ih, gi_b, G3_, 1, 1.0f, 0, 0);
    // f = mean_a (aux_a @ W_fh_a^T + b_fh_a)
    proj_gemm<<<dim3(M_ / 16, G2_ / 64), blk, 0, stream>>>(
        aux_feats, w_fh, b_fh, f_b, G2_, 2, 0.5f,
        (size_t)M_ * D_, (size_t)G2_ * D_);

    transpose_to_sgb<<<dim3(S_, G3_ / 64), blk, 0, stream>>>(gi_b, gi_t, G3_);
    transpose_to_sgb<<<dim3(S_, G2_ / 64), blk, 0, stream>>>(f_b, f_t, G2_);
    transpose_h0<<<dim3(H_ / 64), blk, 0, stream>>>(hx, ht);  // ht buffer 0

    for (int t = 0; t < S_; ++t) {
        const float* hi = ht + (size_t)(t & 1) * (H_ * B_);
        float*       ho = ht + (size_t)((t + 1) & 1) * (H_ * B_);
        scan_step<<<dim3(H_ / 4), blk, 0, stream>>>(hi, ho, gi_t, f_t, w_hh, b_hh, ys, t);
    }

    transpose_out<<<dim3(S_, H_ / 64), blk, 0, stream>>>(
        ys, out, out + (size_t)B_ * S_ * H_);
}

// Round 2
// 11422.421 us; speedup vs baseline: 1.3747x; 1.3747x over previous
//
#include <hip/hip_runtime.h>
#include <hip/hip_bf16.h>
#include <cstdint>

// Problem constants: H=512, B=64, S=512, D=512, N_AUX=2
#define B_ 64
#define S_ 512
#define D_ 512
#define H_ 512
#define M_ (B_*S_)   // 32768
#define G3_ (3*H_)   // 1536
#define G2_ (2*H_)   // 1024
#define NBLK_SCAN 128   // 32 j-slices x 4 b-groups; <=256 CUs so always co-resident

using floatx4 = __attribute__((ext_vector_type(4))) float;
using shortx8 = __attribute__((ext_vector_type(8))) short;

__device__ __forceinline__ unsigned short f32_to_bf16(float f) {
    union { float f; uint32_t u; } v; v.f = f;
    uint32_t u = v.u;
    return (unsigned short)((u + 0x7FFFu + ((u >> 16) & 1u)) >> 16);
}
__device__ __forceinline__ float bf16_to_f32(unsigned short s) {
    union { uint32_t u; float f; } v; v.u = ((uint32_t)s) << 16;
    return v.f;
}

// ---------------------------------------------------------------------------
// Projection GEMM: out[(s*B+b)][n] = scale * ( sum_a X_a[m,:].W_a[n,:] + sum_a bias_a[n] )
// Writes the scan-ready [S][B][G] layout directly (m = b*S+s -> row s*B+b).
// ---------------------------------------------------------------------------
__global__ __launch_bounds__(256) void proj_gemm(
    const float* __restrict__ X, const float* __restrict__ W,
    const float* __restrict__ bias, unsigned short* __restrict__ out,
    int N, int nstreams, float scale, size_t x_stride, size_t w_stride)
{
    const int m0   = blockIdx.x * 16;
    const int wave = threadIdx.x >> 6;
    const int lane = threadIdx.x & 63;
    const int n0   = blockIdx.y * 64 + wave * 16;
    const int row_a = m0 + (lane & 15);
    const int row_b = n0 + (lane & 15);
    const int koff  = (lane >> 4) * 8;

    floatx4 acc = {0.f, 0.f, 0.f, 0.f};

    for (int a = 0; a < nstreams; ++a) {
        const float* Xa = X + (size_t)a * x_stride + (size_t)row_a * D_ + koff;
        const float* Wa = W + (size_t)a * w_stride + (size_t)row_b * D_ + koff;
        #pragma unroll 4
        for (int kt = 0; kt < D_ / 32; ++kt) {
            const floatx4* px = (const floatx4*)(Xa + kt * 32);
            const floatx4* pw = (const floatx4*)(Wa + kt * 32);
            floatx4 x0 = px[0], x1 = px[1];
            floatx4 w0 = pw[0], w1 = pw[1];
            shortx8 af, bf;
            #pragma unroll
            for (int j = 0; j < 4; ++j) {
                af[j]     = (short)f32_to_bf16(x0[j]);
                af[j + 4] = (short)f32_to_bf16(x1[j]);
                bf[j]     = (short)f32_to_bf16(w0[j]);
                bf[j + 4] = (short)f32_to_bf16(w1[j]);
            }
            acc = __builtin_amdgcn_mfma_f32_16x16x32_bf16(af, bf, acc, 0, 0, 0);
        }
    }

    const int n = n0 + (lane & 15);
    float bsum = 0.f;
    for (int a = 0; a < nstreams; ++a) bsum += bias[a * N + n];
    #pragma unroll
    for (int r = 0; r < 4; ++r) {
        int m = m0 + (lane >> 4) * 4 + r;     // m = b*512 + s
        int b = m >> 9, s = m & (S_ - 1);
        out[((size_t)s * B_ + b) * N + n] = f32_to_bf16(scale * (acc[r] + bsum));
    }
}

// ---------------------------------------------------------------------------
// Scan init: hF[0] = hx (fp32 [B][H]); hA[0] = bf16 A-fragment layout; ctr = 0.
// hA layout: [buf][kt=K/32][bg=B/16][lane][8]  where lane holds
//   h[b = bg*16 + (lane&15)][k = kt*32 + (lane>>4)*8 + u]
// ---------------------------------------------------------------------------
__global__ __launch_bounds__(256) void scan_init(
    const float* __restrict__ hx, float* __restrict__ hF,
    unsigned short* __restrict__ hA, unsigned* __restrict__ ctr)
{
    int idx = blockIdx.x * 256 + threadIdx.x;   // 0..32767
    int b = idx >> 9, j = idx & (H_ - 1);
    float v = hx[idx];
    hF[idx] = v;
    hA[(size_t)((((j >> 5) * 4 + (b >> 4)) * 64) + ((b & 15) | (((j >> 3) & 3) << 4))) * 8 + (j & 7)]
        = f32_to_bf16(v);
    if (idx == 0)
        __hip_atomic_store(ctr, 0u, __ATOMIC_RELAXED, __HIP_MEMORY_SCOPE_AGENT);
}

// ---------------------------------------------------------------------------
// Persistent scan. 128 blocks x 64 threads (1 wave/block). Block (jsl, bg):
// owns j = jsl*16 .. +16 (all 3 gates) for b-group bg. W frags LDS-resident.
// Grid barrier: monotone atomic counter, target (t+1)*NBLK_SCAN.
// ---------------------------------------------------------------------------
__global__ __launch_bounds__(64) void scan_persist(
    const unsigned short* __restrict__ gi,   // [S][B][3H] bf16
    const unsigned short* __restrict__ f,    // [S][B][2H] bf16
    const float* __restrict__ Whh,           // [3H][H] fp32
    const float* __restrict__ bhh,           // [3H]
    float* __restrict__ hF,                  // [2][B*H] fp32
    unsigned short* __restrict__ hA,         // [2][16][4][64][8] bf16
    unsigned* __restrict__ ctr,
    float* __restrict__ out,                 // [B][S][H] fp32
    float* __restrict__ hfin)                // [B][H] fp32
{
    __shared__ shortx8 ldsW[3 * 16 * 64];    // 48 KB: [gate][kt][lane] B-fragments

    const int lane = threadIdx.x;
    const int jsl  = blockIdx.x & 31;
    const int bg   = blockIdx.x >> 5;
    const int j0   = jsl * 16;
    const int jn   = lane & 15;
    const int q    = lane >> 4;
    const int j    = j0 + jn;

    // --- one-time: W fragments -> LDS (each lane fills exactly its own slots)
    #pragma unroll
    for (int g = 0; g < 3; ++g) {
        const float* wrow = Whh + (size_t)(g * H_ + j0 + jn) * H_ + q * 8;
        for (int kt = 0; kt < 16; ++kt) {
            floatx4 w0 = *(const floatx4*)(wrow + kt * 32);
            floatx4 w1 = *(const floatx4*)(wrow + kt * 32 + 4);
            shortx8 wf;
            #pragma unroll
            for (int u = 0; u < 4; ++u) {
                wf[u]     = (short)f32_to_bf16(w0[u]);
                wf[u + 4] = (short)f32_to_bf16(w1[u]);
            }
            ldsW[(g * 16 + kt) * 64 + lane] = wf;
        }
    }
    const float brg = bhh[j], big = bhh[H_ + j], bng = bhh[2 * H_ + j];

    for (int t = 0; t < S_; ++t) {
        const int buf  = t & 1;
        const int nbuf = buf ^ 1;

        floatx4 ar = {0.f,0.f,0.f,0.f}, ai = {0.f,0.f,0.f,0.f}, an = {0.f,0.f,0.f,0.f};
        const unsigned short* hAp = hA + (size_t)buf * (16*4*64*8) + (size_t)(bg * 64 + lane) * 8;
        #pragma unroll 4
        for (int kt = 0; kt < 16; ++kt) {
            shortx8 af = *(const shortx8*)(hAp + (size_t)kt * (4*64*8));
            shortx8 wr = ldsW[(0 * 16 + kt) * 64 + lane];
            shortx8 wi = ldsW[(1 * 16 + kt) * 64 + lane];
            shortx8 wn = ldsW[(2 * 16 + kt) * 64 + lane];
            ar = __builtin_amdgcn_mfma_f32_16x16x32_bf16(af, wr, ar, 0, 0, 0);
            ai = __builtin_amdgcn_mfma_f32_16x16x32_bf16(af, wi, ai, 0, 0, 0);
            an = __builtin_amdgcn_mfma_f32_16x16x32_bf16(af, wn, an, 0, 0, 0);
        }

        #pragma unroll
        for (int r = 0; r < 4; ++r) {
            const int b = bg * 16 + q * 4 + r;
            const unsigned short* gp  = gi + ((size_t)t * B_ + b) * G3_ + j;
            const unsigned short* fp2 = f  + ((size_t)t * B_ + b) * G2_ + j;
            const float ir  = bf16_to_f32(gp[0]);
            const float ii  = bf16_to_f32(gp[H_]);
            const float inn = bf16_to_f32(gp[2 * H_]);
            const float fr  = bf16_to_f32(fp2[0]);
            const float fi  = bf16_to_f32(fp2[H_]);
            const float hprev = hF[(size_t)buf * (B_*H_) + (size_t)b * H_ + j];

            const float hr = ar[r] + brg;
            const float hi = ai[r] + big;
            const float hn = an[r] + bng;
            const float rg = 1.f / (1.f + __expf(-(ir + hr + fr)));
            const float ig = 1.f / (1.f + __expf(-(ii + hi + fi)));
            const float ng = tanhf(inn + rg * hn);
            const float hy = ng + ig * (hprev - ng);

            hF[(size_t)nbuf * (B_*H_) + (size_t)b * H_ + j] = hy;
            hA[(size_t)nbuf * (16*4*64*8)
               + (size_t)((((j >> 5) * 4 + bg) * 64) + ((b & 15) | (((j >> 3) & 3) << 4))) * 8
               + (j & 7)] = f32_to_bf16(hy);
            out[(size_t)b * (S_*H_) + (size_t)t * H_ + j] = hy;
            if (t == S_ - 1) hfin[(size_t)b * H_ + j] = hy;
        }

        // --- grid barrier (device-scope; co-resident grid of 128 blocks)
        __threadfence();
        if (lane == 0) {
            __hip_atomic_fetch_add(ctr, 1u, __ATOMIC_RELEASE, __HIP_MEMORY_SCOPE_AGENT);
            const unsigned tgt = (unsigned)(t + 1) * NBLK_SCAN;
            while (__hip_atomic_load(ctr, __ATOMIC_ACQUIRE, __HIP_MEMORY_SCOPE_AGENT) < tgt) {}
        }
        __threadfence();
    }
}

extern "C" void kernel_launch(void* const* d_in, const int* in_sizes, int n_in,
                              void* d_out, int out_size, void* d_ws, size_t ws_size,
                              hipStream_t stream) {
    const float* input_feats = (const float*)d_in[0];  // [B,S,D]
    const float* aux_feats   = (const float*)d_in[1];  // [A,B,S,D]
    const float* hx          = (const float*)d_in[2];  // [B,H]
    const float* w_ih        = (const float*)d_in[3];  // [3H,D]
    const float* w_fh        = (const float*)d_in[4];  // [A,2H,D]
    const float* b_ih        = (const float*)d_in[5];  // [3H]
    const float* b_fh        = (const float*)d_in[6];  // [A,2H]
    const float* w_hh        = (const float*)d_in[7];  // [3H,H]
    const float* b_hh        = (const float*)d_in[8];  // [3H]
    float* out = (float*)d_out;

    // workspace layout (~168 MB)
    char* ws = (char*)d_ws;
    size_t off = 0;
    unsigned short* gi_t = (unsigned short*)(ws + off); off += (size_t)M_ * G3_ * 2;   // 100.7 MB
    unsigned short* f_t  = (unsigned short*)(ws + off); off += (size_t)M_ * G2_ * 2;   //  67.1 MB
    float*          hF   = (float*)(ws + off);          off += (size_t)2 * B_ * H_ * 4; // 256 KB
    unsigned short* hA   = (unsigned short*)(ws + off); off += (size_t)2 * 16*4*64*8 * 2; // 128 KB
    unsigned*       ctr  = (unsigned*)(ws + off);       off += 64;

    dim3 blk(256);

    // gi = input @ W_ih^T + b_ih   -> [S][B][3H] bf16
    proj_gemm<<<dim3(M_ / 16, G3_ / 64), blk, 0, stream>>>(
        input_feats, w_ih, b_ih, gi_t, G3_, 1, 1.0f, 0, 0);
    // f = mean_a(aux_a @ W_fh_a^T + b_fh_a) -> [S][B][2H] bf16
    proj_gemm<<<dim3(M_ / 16, G2_ / 64), blk, 0, stream>>>(
        aux_feats, w_fh, b_fh, f_t, G2_, 2, 0.5f,
        (size_t)M_ * D_, (size_t)G2_ * D_);

    scan_init<<<dim3(M_ / 256 / 2), blk, 0, stream>>>(hx, hF, hA, ctr);  // 64 blocks cover 32768 elems

    scan_persist<<<dim3(NBLK_SCAN), dim3(64), 0, stream>>>(
        gi_t, f_t, w_hh, b_hh, hF, hA, ctr, out, out + (size_t)B_ * S_ * H_);
}

// Round 3
// 4034.104 us; speedup vs baseline: 3.8925x; 2.8315x over previous
//
#include <hip/hip_runtime.h>
#include <hip/hip_bf16.h>
#include <cstdint>

// Problem constants: H=512, B=64, S=512, D=512, N_AUX=2
#define B_ 64
#define S_ 512
#define D_ 512
#define H_ 512
#define M_ (B_*S_)   // 32768
#define G3_ (3*H_)   // 1536
#define G2_ (2*H_)   // 1024

using floatx4  = __attribute__((ext_vector_type(4))) float;
using shortx8  = __attribute__((ext_vector_type(8))) short;
using ushortx4 = __attribute__((ext_vector_type(4))) unsigned short;

__device__ __forceinline__ unsigned short f32_to_bf16(float f) {
    union { float f; uint32_t u; } v; v.f = f;
    uint32_t u = v.u;
    return (unsigned short)((u + 0x7FFFu + ((u >> 16) & 1u)) >> 16);
}
__device__ __forceinline__ float bf16_to_f32(unsigned short s) {
    union { uint32_t u; float f; } v; v.u = ((uint32_t)s) << 16;
    return v.f;
}

// ---------------------------------------------------------------------------
// fp32 -> bf16 bulk convert (n % 4 == 0)
// ---------------------------------------------------------------------------
__global__ __launch_bounds__(256) void cvt_bf16(
    const float* __restrict__ in, unsigned short* __restrict__ outp, int n)
{
    int idx = (blockIdx.x * 256 + threadIdx.x) * 4;
    if (idx < n) {
        floatx4 v = *(const floatx4*)(in + idx);
        ushortx4 o;
        #pragma unroll
        for (int u = 0; u < 4; ++u) o[u] = f32_to_bf16(v[u]);
        *(ushortx4*)(outp + idx) = o;
    }
}

// ---------------------------------------------------------------------------
// 128x128-tile bf16 MFMA GEMM (m93-style, register-staged LDS, padded rows).
// out[(s*B+b)][n] = scale * ( sum_a A_a[m,:].W_a[n,:] + sum_a bias_a[n] ),
// m = b*S + s. A bf16 [streams][M][512], W bf16 [streams][N][512].
// ---------------------------------------------------------------------------
#define LDK 40   // 32 + 8 shorts pad: row stride 80B = 20 banks -> conflict-free
__global__ __launch_bounds__(256) void proj_gemm128(
    const unsigned short* __restrict__ A, const unsigned short* __restrict__ Wb,
    const float* __restrict__ bias, unsigned short* __restrict__ out,
    int N, int nstreams, float scale, size_t a_stride, size_t w_stride)
{
    __shared__ unsigned short ldsA[128 * LDK];
    __shared__ unsigned short ldsB[128 * LDK];
    const int tid  = threadIdx.x;
    const int lane = tid & 63;
    const int wv   = tid >> 6;
    const int m0   = blockIdx.x * 128;
    const int n0   = blockIdx.y * 128;
    const int wm   = (wv & 1) * 64;
    const int wn   = (wv >> 1) * 64;
    const int srow  = tid >> 2;   // 0..63
    const int spart = tid & 3;    // 0..3

    floatx4 acc[4][4] = {};

    for (int a = 0; a < nstreams; ++a) {
        const unsigned short* Aa = A  + (size_t)a * a_stride;
        const unsigned short* Wa = Wb + (size_t)a * w_stride;
        for (int kt = 0; kt < 16; ++kt) {
            const int k0 = kt * 32;
            #pragma unroll
            for (int h = 0; h < 2; ++h) {
                int row = srow + h * 64;
                *(shortx8*)(ldsA + row * LDK + spart * 8) =
                    *(const shortx8*)(Aa + (size_t)(m0 + row) * 512 + k0 + spart * 8);
                *(shortx8*)(ldsB + row * LDK + spart * 8) =
                    *(const shortx8*)(Wa + (size_t)(n0 + row) * 512 + k0 + spart * 8);
            }
            __syncthreads();
            shortx8 af[4], bf[4];
            #pragma unroll
            for (int i = 0; i < 4; ++i)
                af[i] = *(const shortx8*)(ldsA + (wm + i * 16 + (lane & 15)) * LDK + (lane >> 4) * 8);
            #pragma unroll
            for (int j = 0; j < 4; ++j)
                bf[j] = *(const shortx8*)(ldsB + (wn + j * 16 + (lane & 15)) * LDK + (lane >> 4) * 8);
            #pragma unroll
            for (int i = 0; i < 4; ++i)
                #pragma unroll
                for (int j = 0; j < 4; ++j)
                    acc[i][j] = __builtin_amdgcn_mfma_f32_16x16x32_bf16(af[i], bf[j], acc[i][j], 0, 0, 0);
            __syncthreads();
        }
    }

    #pragma unroll
    for (int j = 0; j < 4; ++j) {
        int n = n0 + wn + j * 16 + (lane & 15);
        float bsum = 0.f;
        for (int a = 0; a < nstreams; ++a) bsum += bias[a * N + n];
        #pragma unroll
        for (int i = 0; i < 4; ++i) {
            #pragma unroll
            for (int r = 0; r < 4; ++r) {
                int m = m0 + wm + i * 16 + (lane >> 4) * 4 + r;
                int b = m >> 9, s = m & (S_ - 1);
                out[((size_t)s * B_ + b) * N + n] = f32_to_bf16(scale * (acc[i][j][r] + bsum));
            }
        }
    }
}

// ---------------------------------------------------------------------------
// Transpose bf16 [S][B][G] -> [S][G][B]
// ---------------------------------------------------------------------------
__global__ __launch_bounds__(256) void transpose_to_sgb(
    const unsigned short* __restrict__ in, unsigned short* __restrict__ out, int G)
{
    __shared__ unsigned short tile[64][66];
    const int s  = blockIdx.x;
    const int g0 = blockIdx.y * 64;
    const int c  = threadIdx.x & 63;
    const int r0 = threadIdx.x >> 6;
    #pragma unroll
    for (int i = 0; i < 16; ++i) {
        int b = r0 * 16 + i;
        tile[b][c] = in[((size_t)s * B_ + b) * G + g0 + c];      // coalesced in g
    }
    __syncthreads();
    #pragma unroll
    for (int i = 0; i < 16; ++i) {
        int gg = r0 * 16 + i;
        out[((size_t)s * G + g0 + gg) * B_ + c] = tile[c][gg];   // coalesced in b
    }
}

// ---------------------------------------------------------------------------
// Scan init: hA[0] from hx in A-fragment layout; zero flags.
// hA short index for (b,j): ((j>>5)*4+(b>>4))*512 + ((j>>3)&3)*128 + (b&15)*8 + (j&7)
// ---------------------------------------------------------------------------
__global__ __launch_bounds__(256) void scan_init(
    const float* __restrict__ hx, unsigned short* __restrict__ hA,
    unsigned* __restrict__ flags)
{
    int idx = blockIdx.x * 256 + threadIdx.x;   // 0..32767 (grid 128!)
    int b = idx >> 9, j = idx & (H_ - 1);
    hA[(size_t)((j >> 5) * 4 + (b >> 4)) * 512 + ((j >> 3) & 3) * 128 + (b & 15) * 8 + (j & 7)]
        = f32_to_bf16(hx[idx]);
    if (idx < 128) flags[idx] = 0;
}

// ---------------------------------------------------------------------------
// Persistent scan. 128 blocks x 64 threads (1 wave). Block = (bg = blk>>5,
// jsl = blk&31): owns j = jsl*16..+16, b-group bg (16 b). W frags in LDS.
// Barrier: per-bg flag array (32 flags), release store + read-only poll.
// ---------------------------------------------------------------------------
__global__ __launch_bounds__(64) void scan_persist(
    const unsigned short* __restrict__ git,  // [S][3H][B] bf16
    const unsigned short* __restrict__ ft,   // [S][2H][B] bf16
    const float* __restrict__ Whh,           // [3H][H]
    const float* __restrict__ bhh,           // [3H]
    const float* __restrict__ hx,            // [B][H]
    unsigned short* __restrict__ hA,         // [2][32768] bf16
    unsigned* __restrict__ flags,            // [128]
    float* __restrict__ out,                 // [B][S][H]
    float* __restrict__ hfin)                // [B][H]
{
    __shared__ shortx8 ldsW[3 * 16 * 64];    // 48 KB
    __shared__ unsigned short repack[256];   // 512 B

    const int lane = threadIdx.x;
    const int jsl  = blockIdx.x & 31;
    const int bg   = blockIdx.x >> 5;
    const int j0   = jsl * 16;
    const int jn   = lane & 15;
    const int q    = lane >> 4;
    const int j    = j0 + jn;
    const int b0   = bg * 16 + q * 4;

    // one-time: W fragments -> LDS
    #pragma unroll
    for (int g = 0; g < 3; ++g) {
        const float* wrow = Whh + (size_t)(g * H_ + j0 + jn) * H_ + q * 8;
        for (int kt = 0; kt < 16; ++kt) {
            floatx4 w0 = *(const floatx4*)(wrow + kt * 32);
            floatx4 w1 = *(const floatx4*)(wrow + kt * 32 + 4);
            shortx8 wf;
            #pragma unroll
            for (int u = 0; u < 4; ++u) {
                wf[u]     = (short)f32_to_bf16(w0[u]);
                wf[u + 4] = (short)f32_to_bf16(w1[u]);
            }
            ldsW[(g * 16 + kt) * 64 + lane] = wf;
        }
    }
    const float brg = bhh[j], big = bhh[H_ + j], bng = bhh[2 * H_ + j];

    float hprev[4];
    #pragma unroll
    for (int r = 0; r < 4; ++r) hprev[r] = hx[(size_t)(b0 + r) * H_ + j];

    // gate prefetch registers (t = 0)
    ushortx4 pgr, pgi, pgn, pfr, pfi;
    {
        const unsigned short* gp = git + ((size_t)j) * B_ + b0;
        pgr = *(const ushortx4*)(gp);
        pgi = *(const ushortx4*)(gp + (size_t)H_ * B_);
        pgn = *(const ushortx4*)(gp + (size_t)2 * H_ * B_);
        const unsigned short* fp = ft + ((size_t)j) * B_ + b0;
        pfr = *(const ushortx4*)(fp);
        pfi = *(const ushortx4*)(fp + (size_t)H_ * B_);
    }

    const int slab = (jsl >> 1) * 4 + bg;
    unsigned* myflags = flags + bg * 32;

    for (int t = 0; t < S_; ++t) {
        const int buf = t & 1, nbuf = buf ^ 1;

        floatx4 ar = {0.f,0.f,0.f,0.f}, ai = {0.f,0.f,0.f,0.f}, an = {0.f,0.f,0.f,0.f};
        const unsigned short* hAp = hA + (size_t)buf * 32768 + (size_t)(bg * 64 + lane) * 8;
        #pragma unroll 4
        for (int kt = 0; kt < 16; ++kt) {
            shortx8 af = *(const shortx8*)(hAp + (size_t)kt * 2048);
            ar = __builtin_amdgcn_mfma_f32_16x16x32_bf16(af, ldsW[(0 * 16 + kt) * 64 + lane], ar, 0, 0, 0);
            ai = __builtin_amdgcn_mfma_f32_16x16x32_bf16(af, ldsW[(1 * 16 + kt) * 64 + lane], ai, 0, 0, 0);
            an = __builtin_amdgcn_mfma_f32_16x16x32_bf16(af, ldsW[(2 * 16 + kt) * 64 + lane], an, 0, 0, 0);
        }

        float hy[4];
        #pragma unroll
        for (int r = 0; r < 4; ++r) {
            const float cr = bf16_to_f32(pgr[r]) + bf16_to_f32(pfr[r]);
            const float ci = bf16_to_f32(pgi[r]) + bf16_to_f32(pfi[r]);
            const float cn = bf16_to_f32(pgn[r]);
            const float rg = 1.f / (1.f + __expf(-(cr + ar[r] + brg)));
            const float ig = 1.f / (1.f + __expf(-(ci + ai[r] + big)));
            const float ng = tanhf(cn + rg * (an[r] + bng));
            hy[r] = ng + ig * (hprev[r] - ng);
            hprev[r] = hy[r];
            repack[(jn >> 3) * 128 + (q * 4 + r) * 8 + (jn & 7)] = f32_to_bf16(hy[r]);
        }
        __syncthreads();   // LDS repack visibility within the wave
        *(ushortx4*)(hA + (size_t)nbuf * 32768 + (size_t)slab * 512 + (jsl & 1) * 256 + lane * 4)
            = *(const ushortx4*)(repack + lane * 4);

        if (t < S_ - 1) {
            __builtin_amdgcn_fence(__ATOMIC_RELEASE, "agent");   // drain hA store to coherent point
            if (lane == 0)
                __hip_atomic_store(&myflags[jsl], (unsigned)(t + 1),
                                   __ATOMIC_RELAXED, __HIP_MEMORY_SCOPE_AGENT);
            // off-critical-path work drains during the spin:
            #pragma unroll
            for (int r = 0; r < 4; ++r)
                out[(size_t)(b0 + r) * (S_ * H_) + (size_t)t * H_ + j] = hy[r];
            {   // prefetch gates for t+1
                const unsigned short* gp = git + ((size_t)(t + 1) * G3_ + j) * B_ + b0;
                pgr = *(const ushortx4*)(gp);
                pgi = *(const ushortx4*)(gp + (size_t)H_ * B_);
                pgn = *(const ushortx4*)(gp + (size_t)2 * H_ * B_);
                const unsigned short* fp = ft + ((size_t)(t + 1) * G2_ + j) * B_ + b0;
                pfr = *(const ushortx4*)(fp);
                pfi = *(const ushortx4*)(fp + (size_t)H_ * B_);
            }
            const unsigned tgt = (unsigned)(t + 1);
            unsigned v;
            do {
                v = __hip_atomic_load(&myflags[lane & 31], __ATOMIC_RELAXED,
                                      __HIP_MEMORY_SCOPE_AGENT);
            } while (__any((int)(v < tgt)));
            __builtin_amdgcn_fence(__ATOMIC_ACQUIRE, "agent");   // invalidate L1 before hA reads
        } else {
            #pragma unroll
            for (int r = 0; r < 4; ++r) {
                out[(size_t)(b0 + r) * (S_ * H_) + (size_t)t * H_ + j] = hy[r];
                hfin[(size_t)(b0 + r) * H_ + j] = hy[r];
            }
        }
    }
}

extern "C" void kernel_launch(void* const* d_in, const int* in_sizes, int n_in,
                              void* d_out, int out_size, void* d_ws, size_t ws_size,
                              hipStream_t stream) {
    const float* input_feats = (const float*)d_in[0];  // [B,S,D]
    const float* aux_feats   = (const float*)d_in[1];  // [A,B,S,D]
    const float* hx          = (const float*)d_in[2];  // [B,H]
    const float* w_ih        = (const float*)d_in[3];  // [3H,D]
    const float* w_fh        = (const float*)d_in[4];  // [A,2H,D]
    const float* b_ih        = (const float*)d_in[5];  // [3H]
    const float* b_fh        = (const float*)d_in[6];  // [A,2H]
    const float* w_hh        = (const float*)d_in[7];  // [3H,H]
    const float* b_hh        = (const float*)d_in[8];  // [3H]
    float* out = (float*)d_out;

    // workspace (~340 MB). X_bf/AUX_bf live inside the git/ft zone (dead by
    // the time the transposes write git/ft).
    char* ws = (char*)d_ws;
    size_t off = 0;
    unsigned short* git  = (unsigned short*)(ws + off); off += (size_t)S_ * G3_ * B_ * 2; // 100.7 MB
    unsigned short* ft   = (unsigned short*)(ws + off); off += (size_t)S_ * G2_ * B_ * 2; //  67.1 MB
    unsigned short* gi_b = (unsigned short*)(ws + off); off += (size_t)M_ * G3_ * 2;      // 100.7 MB
    unsigned short* f_b  = (unsigned short*)(ws + off); off += (size_t)M_ * G2_ * 2;      //  67.1 MB
    unsigned short* Wih_bf = (unsigned short*)(ws + off); off += (size_t)G3_ * D_ * 2;    //   1.6 MB
    unsigned short* Wfh_bf = (unsigned short*)(ws + off); off += (size_t)2 * G2_ * D_ * 2;//   2.1 MB
    unsigned short* hA   = (unsigned short*)(ws + off); off += (size_t)2 * 32768 * 2;     // 128 KB
    unsigned*       flags = (unsigned*)(ws + off);      off += 512;
    unsigned short* X_bf   = git;                        // 33.6 MB, inside git zone
    unsigned short* AUX_bf = git + (size_t)M_ * D_;      // 67.1 MB, inside git zone

    dim3 blk(256);

    // bf16 pre-converts
    cvt_bf16<<<dim3((M_ * D_) / 1024), blk, 0, stream>>>(input_feats, X_bf, M_ * D_);
    cvt_bf16<<<dim3((2 * M_ * D_) / 1024), blk, 0, stream>>>(aux_feats, AUX_bf, 2 * M_ * D_);
    cvt_bf16<<<dim3((G3_ * D_) / 1024), blk, 0, stream>>>(w_ih, Wih_bf, G3_ * D_);
    cvt_bf16<<<dim3((2 * G2_ * D_) / 1024), blk, 0, stream>>>(w_fh, Wfh_bf, 2 * G2_ * D_);

    // projections (128x128 tiles)
    proj_gemm128<<<dim3(M_ / 128, G3_ / 128), blk, 0, stream>>>(
        X_bf, Wih_bf, b_ih, gi_b, G3_, 1, 1.0f, 0, 0);
    proj_gemm128<<<dim3(M_ / 128, G2_ / 128), blk, 0, stream>>>(
        AUX_bf, Wfh_bf, b_fh, f_b, G2_, 2, 0.5f,
        (size_t)M_ * D_, (size_t)G2_ * D_);

    // transpose to [S][G][B] (clobbers X_bf/AUX_bf — dead)
    transpose_to_sgb<<<dim3(S_, G3_ / 64), blk, 0, stream>>>(gi_b, git, G3_);
    transpose_to_sgb<<<dim3(S_, G2_ / 64), blk, 0, stream>>>(f_b, ft, G2_);

    scan_init<<<dim3(M_ / 256), blk, 0, stream>>>(hx, hA, flags);   // full 32768 coverage

    scan_persist<<<dim3(128), dim3(64), 0, stream>>>(
        git, ft, w_hh, b_hh, hx, hA, flags, out, out + (size_t)B_ * S_ * H_);
}